// Round 4
// baseline (1356.342 us; speedup 1.0000x reference)
//
#include <hip/hip_runtime.h>

// Problem constants
#define CDIM 256        // token_size (channels)
#define CB   4096       // codebook size
#define HW   1024       // 32*32
#define NTOK 32768      // 32*32*32 tokens
#define NELEM 8388608   // 32*256*32*32

// k1 tiling
#define MT 128          // tokens per block
#define NT 128          // codes per tile
#define KCH 32          // K-chunk
#define CSPLIT 4        // codebook split -> grid 1024 -> 4 blocks/CU (LDS = exactly 40 KiB)
#define ZSTRIDE 192     // 16 groups x (8 tokens + 4 pad) floats per k-row

// ---------------- kernel 0: codebook row norms + zero the loss accumulator ----------------
__global__ __launch_bounds__(256) void k0_enorm(const float* __restrict__ emb,
                                                float* __restrict__ enorm2,
                                                float* __restrict__ S) {
    const int code = blockIdx.x * 256 + threadIdx.x;   // grid = 16 blocks
    const float4* row = (const float4*)(emb + (size_t)code * CDIM);
    float s = 0.f;
#pragma unroll 8
    for (int i = 0; i < CDIM / 4; ++i) {
        float4 v = row[i];
        s += v.x * v.x + v.y * v.y + v.z * v.z + v.w * v.w;
    }
    enorm2[code] = s;
    if (blockIdx.x == 0 && threadIdx.x == 0) *S = 0.f;
}

// ---------------- kernel 0z: per-token ||z||^2 ----------------
// Any fp32 summation order works: argmin decisions are invariant to
// grid-multiple translations of znorm2.
__global__ __launch_bounds__(256) void k0z_znorm(const float* __restrict__ z,
                                                 float* __restrict__ znorm2) {
    const int tok = blockIdx.x * 256 + threadIdx.x;    // grid = 128 blocks
    const int b   = tok >> 10;
    const int hw  = tok & 1023;
    const float* zp = z + (size_t)b * (CDIM * HW) + hw;
    float s0 = 0.f, s1 = 0.f, s2 = 0.f, s3 = 0.f;
#pragma unroll 4
    for (int c = 0; c < CDIM; c += 4) {
        float a = zp[(size_t)(c + 0) * HW];
        float b2 = zp[(size_t)(c + 1) * HW];
        float c2 = zp[(size_t)(c + 2) * HW];
        float d2 = zp[(size_t)(c + 3) * HW];
        s0 += a * a; s1 += b2 * b2; s2 += c2 * c2; s3 += d2 * d2;
    }
    znorm2[tok] = (s0 + s1) + (s2 + s3);
}

// ---------------- kernel 1: tiled GEMM-argmin over a codebook slice ----------------
// d_k = fl32( fl32(znorm2 + enorm2_k) - 2*dot_k ); per-(token,split) best -> ws.
__global__ __launch_bounds__(256, 4) void k1_argmin(const float* __restrict__ z,
                                                    const float* __restrict__ emb,
                                                    const float* __restrict__ enorm2,
                                                    const float* __restrict__ znorm2,
                                                    float* __restrict__ wsd,
                                                    int* __restrict__ wsk) {
    // Zs: [k][group g][8 tokens + 4 pad] -> read start bank = (12g)%32, max 2-way (free)
    __shared__ float Zs[KCH][ZSTRIDE];  // 24576 B
    // Es: stride 128 (no pad needed): staging-store bank = code%32, lane pairs 2-way (free);
    // fragment reads are quarter-wave broadcasts at banks {0,8,16,24}.
    __shared__ float Es[KCH][NT];       // 16384 B  -> total 40960 B = 4 blocks/CU exactly

    const int tid   = threadIdx.x;
    const int split = blockIdx.x & (CSPLIT - 1);
    const int tok0  = (blockIdx.x >> 2) * MT;  // 256 token-groups x CSPLIT
    const int b     = tok0 >> 10;
    const int hw0   = tok0 & 1023;             // MT | 1024 -> block never crosses b
    const float* zb = z + (size_t)b * (CDIM * HW) + hw0;

    const int tx = tid & 15;                   // tokens 8*tx .. 8*tx+7
    const int ty = tid >> 4;                   // codes  8*ty .. 8*ty+7 (per tile)

    // per-token ||z||^2 (fp32, as the reference adds it)
    float4 zn0 = *(const float4*)(znorm2 + tok0 + 8 * tx);
    float4 zn1 = *(const float4*)(znorm2 + tok0 + 8 * tx + 4);
    const float zn[8] = {zn0.x, zn0.y, zn0.z, zn0.w, zn1.x, zn1.y, zn1.z, zn1.w};

    float bestd[8];
    int   bestk[8];
#pragma unroll
    for (int i = 0; i < 8; ++i) { bestd[i] = 1e30f; bestk[i] = 0; }

    for (int ct = 0; ct < CB / CSPLIT / NT; ++ct) {       // 8 tiles
        const int code0 = split * (CB / CSPLIT) + ct * NT;
        float acc[8][8];
#pragma unroll
        for (int i = 0; i < 8; ++i)
#pragma unroll
            for (int j = 0; j < 8; ++j) acc[i][j] = 0.f;

        for (int kc = 0; kc < CDIM / KCH; ++kc) {
            const int c0 = kc * KCH;
            __syncthreads();
            // stage Z chunk: 128 tokens x 32 c (coalesced float4 along tokens,
            // stored into the group-padded layout)
            {
                const int m = tid & 31;                  // tokens 4m..4m+3
                const int zoff = 12 * (m >> 1) + 4 * (m & 1);
                int kk = tid >> 5;                       // 0..7, 4 passes
#pragma unroll
                for (int p = 0; p < 4; ++p, kk += 8) {
                    float4 v = *(const float4*)(zb + (size_t)(c0 + kk) * HW + 4 * m);
                    *(float4*)&Zs[kk][zoff] = v;
                }
            }
            // stage E chunk: 128 codes x 32 c (float4 along c, transposed scalar stores)
            {
                const int code  = tid >> 1;
                const int kbase = (tid & 1) * 16;
                const float* er = emb + (size_t)(code0 + code) * CDIM + c0 + kbase;
#pragma unroll
                for (int q = 0; q < 4; ++q) {
                    float4 v = *(const float4*)(er + 4 * q);
                    Es[kbase + 4 * q + 0][code] = v.x;
                    Es[kbase + 4 * q + 1][code] = v.y;
                    Es[kbase + 4 * q + 2][code] = v.z;
                    Es[kbase + 4 * q + 3][code] = v.w;
                }
            }
            __syncthreads();
#pragma unroll
            for (int k = 0; k < KCH; ++k) {
                float4 a0 = *(const float4*)&Zs[k][12 * tx];
                float4 a1 = *(const float4*)&Zs[k][12 * tx + 4];
                float4 b0 = *(const float4*)&Es[k][8 * ty];
                float4 b1 = *(const float4*)&Es[k][8 * ty + 4];
                float av[8] = {a0.x, a0.y, a0.z, a0.w, a1.x, a1.y, a1.z, a1.w};
                float bv[8] = {b0.x, b0.y, b0.z, b0.w, b1.x, b1.y, b1.z, b1.w};
#pragma unroll
                for (int i = 0; i < 8; ++i)
#pragma unroll
                    for (int j = 0; j < 8; ++j) acc[i][j] += av[i] * bv[j];
            }
        }
        // epilogue: replicate reference rounding chain:
        //   t1 = fl(zn + en_k); d = fl(t1 - 2*dot)
        float4 e0 = *(const float4*)(enorm2 + code0 + 8 * ty);
        float4 e1 = *(const float4*)(enorm2 + code0 + 8 * ty + 4);
        const float en[8] = {e0.x, e0.y, e0.z, e0.w, e1.x, e1.y, e1.z, e1.w};
#pragma unroll
        for (int i = 0; i < 8; ++i) {
#pragma unroll
            for (int j = 0; j < 8; ++j) {
                float t1 = zn[i] + en[j];
                float d  = t1 - 2.f * acc[i][j];
                if (d < bestd[i]) { bestd[i] = d; bestk[i] = code0 + 8 * ty + j; }
            }
        }
    }

    // cross-ty reduction via LDS reuse; ties -> lowest index
    __syncthreads();
    float* redd = &Zs[0][0];       // need 2048 floats; 6144 available
    int*   redk = (int*)&Es[0][0]; // need 2048 ints;   4096 available
#pragma unroll
    for (int i = 0; i < 8; ++i) {
        redd[ty * MT + 8 * tx + i] = bestd[i];
        redk[ty * MT + 8 * tx + i] = bestk[i];
    }
    __syncthreads();
    if (tid < MT) {
        float bd = 1e30f; int bk = 0x7fffffff;
        for (int t = 0; t < 16; ++t) {
            float d2 = redd[t * MT + tid];
            int   k2 = redk[t * MT + tid];
            if (d2 < bd || (d2 == bd && k2 < bk)) { bd = d2; bk = k2; }
        }
        wsd[(size_t)split * NTOK + tok0 + tid] = bd;
        wsk[(size_t)split * NTOK + tok0 + tid] = bk;
    }
}

// ---------------- kernel 4: merge splits, emit indices, accumulate loss sum ----------------
__global__ __launch_bounds__(256) void k4_merge(const float* __restrict__ wsd,
                                                const int* __restrict__ wsk,
                                                float* __restrict__ idxf,
                                                float* __restrict__ S) {
    __shared__ float red[256];
    const int t = blockIdx.x * 256 + threadIdx.x;   // grid = 128 blocks
    float bd = wsd[t];
    int   bk = wsk[t];
#pragma unroll
    for (int s = 1; s < CSPLIT; ++s) {
        float d = wsd[(size_t)s * NTOK + t];
        int   k = wsk[(size_t)s * NTOK + t];
        if (d < bd) { bd = d; bk = k; }   // tie -> lower split = lower index (argmin semantics)
    }
    idxf[t] = (float)bk;
    red[threadIdx.x] = bd;
    __syncthreads();
    for (int o = 128; o > 0; o >>= 1) {
        if (threadIdx.x < o) red[threadIdx.x] += red[threadIdx.x + o];
        __syncthreads();
    }
    if (threadIdx.x == 0) atomicAdd(S, red[0]);
}

// ---------------- kernel 2: scatter z_q = emb[idx] into [b,c,h,w] layout ----------------
__global__ __launch_bounds__(256) void k2_scatter(const float* __restrict__ emb,
                                                  const float* __restrict__ idxf,
                                                  float* __restrict__ zq) {
    __shared__ int ks[64];
    const int tid  = threadIdx.x;
    const int tok0 = blockIdx.x * 64;          // grid = 512 blocks
    const int b    = tok0 >> 10;
    const int hw0  = tok0 & 1023;
    if (tid < 64) ks[tid] = (int)idxf[tok0 + tid];
    __syncthreads();
    const int t4 = (tid & 15) * 4;
    const int ka = ks[t4], kb = ks[t4 + 1], kc = ks[t4 + 2], kd = ks[t4 + 3];
    float* outb = zq + (size_t)b * (CDIM * HW) + hw0 + t4;
    int c = tid >> 4;                          // 16 c per pass, 16 passes
#pragma unroll
    for (int p = 0; p < 16; ++p, c += 16) {
        float4 v;
        v.x = emb[(size_t)ka * CDIM + c];
        v.y = emb[(size_t)kb * CDIM + c];
        v.z = emb[(size_t)kc * CDIM + c];
        v.w = emb[(size_t)kd * CDIM + c];
        *(float4*)(outb + (size_t)c * HW) = v;   // coalesced float4 store
    }
}

// ---------------- kernel 3: the three loss scalars ----------------
// S = sum_n min_k ||z_n - e_k||^2 (quantized d; error ~1e-3 vs ~2% threshold)
__global__ void k3_scalars(const float* __restrict__ S, float* __restrict__ out) {
    const float mse = *S / (float)NELEM;
    out[0] = 1.25f * mse;   // loss
    out[1] = 0.25f * mse;   // commitment_loss
    out[2] = mse;           // codebook_loss
}

extern "C" void kernel_launch(void* const* d_in, const int* in_sizes, int n_in,
                              void* d_out, int out_size, void* d_ws, size_t ws_size,
                              hipStream_t stream) {
    const float* z   = (const float*)d_in[0];   // [32,256,32,32]
    const float* emb = (const float*)d_in[1];   // [4096,256]
    float* out  = (float*)d_out;                // zq(8388608) | 3 scalars | idx(32768) as f32
    float* wsf  = (float*)d_ws;
    float* S      = wsf;                        // 1 float
    float* enorm2 = wsf + 64;                   // 4096
    float* znorm2 = wsf + 64 + CB;              // 32768
    float* wsd    = wsf + 64 + CB + NTOK;       // CSPLIT*32768
    int*   wsk    = (int*)(wsd + (size_t)CSPLIT * NTOK);  // CSPLIT*32768
    float* idxf   = out + NELEM + 3;

    hipLaunchKernelGGL(k0_enorm,  dim3(CB / 256),           dim3(256), 0, stream, emb, enorm2, S);
    hipLaunchKernelGGL(k0z_znorm, dim3(NTOK / 256),         dim3(256), 0, stream, z, znorm2);
    hipLaunchKernelGGL(k1_argmin, dim3(NTOK / MT * CSPLIT), dim3(256), 0, stream,
                       z, emb, enorm2, znorm2, wsd, wsk);
    hipLaunchKernelGGL(k4_merge,  dim3(NTOK / 256),         dim3(256), 0, stream, wsd, wsk, idxf, S);
    hipLaunchKernelGGL(k2_scatter, dim3(NTOK / 64),         dim3(256), 0, stream, emb, idxf, out);
    hipLaunchKernelGGL(k3_scalars, dim3(1), dim3(1), 0, stream, S, out + NELEM);
}

// Round 5
// 898.032 us; speedup vs baseline: 1.5103x; 1.5103x over previous
//
#include <hip/hip_runtime.h>

// Problem constants
#define CDIM 256        // token_size (channels)
#define CB   4096       // codebook size
#define HW   1024       // 32*32
#define NTOK 32768      // 32*32*32 tokens
#define NELEM 8388608   // 32*256*32*32

// k1 tiling
#define MT 128          // tokens per block
#define NT 128          // codes per tile
#define KCH 32          // K-chunk
#define CSPLIT 4        // codebook split -> grid 1024 -> 4 blocks/CU (LDS = exactly 40 KiB)
#define ZSTRIDE 192     // 16 groups x (8 tokens + 4 pad) floats per k-row

// NOTE: __launch_bounds__(256,4) round-4 experiment: allocator capped VGPR at 64,
// the 8x8 accumulator spilled to scratch (WRITE_SIZE 512KB -> 1.9GB), dur +57%.
// Plain (256) compiles to 104 VGPR = 4 waves/SIMD naturally. Do not re-add.

// ---------------- kernel 0: codebook row norms + zero the loss accumulator ----------------
__global__ __launch_bounds__(256) void k0_enorm(const float* __restrict__ emb,
                                                float* __restrict__ enorm2,
                                                float* __restrict__ S) {
    const int code = blockIdx.x * 256 + threadIdx.x;   // grid = 16 blocks
    const float4* row = (const float4*)(emb + (size_t)code * CDIM);
    float s = 0.f;
#pragma unroll 8
    for (int i = 0; i < CDIM / 4; ++i) {
        float4 v = row[i];
        s += v.x * v.x + v.y * v.y + v.z * v.z + v.w * v.w;
    }
    enorm2[code] = s;
    if (blockIdx.x == 0 && threadIdx.x == 0) *S = 0.f;
}

// ---------------- kernel 0z: per-token ||z||^2 ----------------
// Any fp32 summation order works: argmin decisions are invariant to
// grid-multiple translations of znorm2.
__global__ __launch_bounds__(256) void k0z_znorm(const float* __restrict__ z,
                                                 float* __restrict__ znorm2) {
    const int tok = blockIdx.x * 256 + threadIdx.x;    // grid = 128 blocks
    const int b   = tok >> 10;
    const int hw  = tok & 1023;
    const float* zp = z + (size_t)b * (CDIM * HW) + hw;
    float s0 = 0.f, s1 = 0.f, s2 = 0.f, s3 = 0.f;
#pragma unroll 4
    for (int c = 0; c < CDIM; c += 4) {
        float a = zp[(size_t)(c + 0) * HW];
        float b2 = zp[(size_t)(c + 1) * HW];
        float c2 = zp[(size_t)(c + 2) * HW];
        float d2 = zp[(size_t)(c + 3) * HW];
        s0 += a * a; s1 += b2 * b2; s2 += c2 * c2; s3 += d2 * d2;
    }
    znorm2[tok] = (s0 + s1) + (s2 + s3);
}

// ---------------- kernel 1: tiled GEMM-argmin over a codebook slice ----------------
// d_k = fl32( fl32(znorm2 + enorm2_k) - 2*dot_k ); per-(token,split) best -> ws.
__global__ __launch_bounds__(256) void k1_argmin(const float* __restrict__ z,
                                                 const float* __restrict__ emb,
                                                 const float* __restrict__ enorm2,
                                                 const float* __restrict__ znorm2,
                                                 float* __restrict__ wsd,
                                                 int* __restrict__ wsk) {
    // Zs: [k][group g][8 tokens + 4 pad] -> read start bank = (12g)%32, max 2-way (free)
    __shared__ float Zs[KCH][ZSTRIDE];  // 24576 B
    // Es: stride 128 (no pad): staging-store bank = code%32, lane pairs 2-way (free);
    // fragment reads are quarter-wave broadcasts at banks {0,8,16,24}.
    __shared__ float Es[KCH][NT];       // 16384 B  -> total 40960 B = 4 blocks/CU exactly

    const int tid   = threadIdx.x;
    const int split = blockIdx.x & (CSPLIT - 1);
    const int tok0  = (blockIdx.x >> 2) * MT;  // 256 token-groups x CSPLIT
    const int b     = tok0 >> 10;
    const int hw0   = tok0 & 1023;             // MT | 1024 -> block never crosses b
    const float* zb = z + (size_t)b * (CDIM * HW) + hw0;

    const int tx = tid & 15;                   // tokens 8*tx .. 8*tx+7
    const int ty = tid >> 4;                   // codes  8*ty .. 8*ty+7 (per tile)

    // per-token ||z||^2 (fp32, as the reference adds it)
    float4 zn0 = *(const float4*)(znorm2 + tok0 + 8 * tx);
    float4 zn1 = *(const float4*)(znorm2 + tok0 + 8 * tx + 4);
    const float zn[8] = {zn0.x, zn0.y, zn0.z, zn0.w, zn1.x, zn1.y, zn1.z, zn1.w};

    float bestd[8];
    int   bestk[8];
#pragma unroll
    for (int i = 0; i < 8; ++i) { bestd[i] = 1e30f; bestk[i] = 0; }

    for (int ct = 0; ct < CB / CSPLIT / NT; ++ct) {       // 8 tiles
        const int code0 = split * (CB / CSPLIT) + ct * NT;
        float acc[8][8];
#pragma unroll
        for (int i = 0; i < 8; ++i)
#pragma unroll
            for (int j = 0; j < 8; ++j) acc[i][j] = 0.f;

        for (int kc = 0; kc < CDIM / KCH; ++kc) {
            const int c0 = kc * KCH;
            __syncthreads();
            // stage Z chunk: 128 tokens x 32 c (coalesced float4 along tokens,
            // stored into the group-padded layout)
            {
                const int m = tid & 31;                  // tokens 4m..4m+3
                const int zoff = 12 * (m >> 1) + 4 * (m & 1);
                int kk = tid >> 5;                       // 0..7, 4 passes
#pragma unroll
                for (int p = 0; p < 4; ++p, kk += 8) {
                    float4 v = *(const float4*)(zb + (size_t)(c0 + kk) * HW + 4 * m);
                    *(float4*)&Zs[kk][zoff] = v;
                }
            }
            // stage E chunk: 128 codes x 32 c (float4 along c, transposed scalar stores)
            {
                const int code  = tid >> 1;
                const int kbase = (tid & 1) * 16;
                const float* er = emb + (size_t)(code0 + code) * CDIM + c0 + kbase;
#pragma unroll
                for (int q = 0; q < 4; ++q) {
                    float4 v = *(const float4*)(er + 4 * q);
                    Es[kbase + 4 * q + 0][code] = v.x;
                    Es[kbase + 4 * q + 1][code] = v.y;
                    Es[kbase + 4 * q + 2][code] = v.z;
                    Es[kbase + 4 * q + 3][code] = v.w;
                }
            }
            __syncthreads();
#pragma unroll
            for (int k = 0; k < KCH; ++k) {
                float4 a0 = *(const float4*)&Zs[k][12 * tx];
                float4 a1 = *(const float4*)&Zs[k][12 * tx + 4];
                float4 b0 = *(const float4*)&Es[k][8 * ty];
                float4 b1 = *(const float4*)&Es[k][8 * ty + 4];
                float av[8] = {a0.x, a0.y, a0.z, a0.w, a1.x, a1.y, a1.z, a1.w};
                float bv[8] = {b0.x, b0.y, b0.z, b0.w, b1.x, b1.y, b1.z, b1.w};
#pragma unroll
                for (int i = 0; i < 8; ++i)
#pragma unroll
                    for (int j = 0; j < 8; ++j) acc[i][j] += av[i] * bv[j];
            }
        }
        // epilogue: replicate reference rounding chain:
        //   t1 = fl(zn + en_k); d = fl(t1 - 2*dot)
        float4 e0 = *(const float4*)(enorm2 + code0 + 8 * ty);
        float4 e1 = *(const float4*)(enorm2 + code0 + 8 * ty + 4);
        const float en[8] = {e0.x, e0.y, e0.z, e0.w, e1.x, e1.y, e1.z, e1.w};
#pragma unroll
        for (int i = 0; i < 8; ++i) {
#pragma unroll
            for (int j = 0; j < 8; ++j) {
                float t1 = zn[i] + en[j];
                float d  = t1 - 2.f * acc[i][j];
                if (d < bestd[i]) { bestd[i] = d; bestk[i] = code0 + 8 * ty + j; }
            }
        }
    }

    // cross-ty reduction via LDS reuse; ties -> lowest index
    __syncthreads();
    float* redd = &Zs[0][0];       // need 2048 floats; 6144 available
    int*   redk = (int*)&Es[0][0]; // need 2048 ints;   4096 available
#pragma unroll
    for (int i = 0; i < 8; ++i) {
        redd[ty * MT + 8 * tx + i] = bestd[i];
        redk[ty * MT + 8 * tx + i] = bestk[i];
    }
    __syncthreads();
    if (tid < MT) {
        float bd = 1e30f; int bk = 0x7fffffff;
        for (int t = 0; t < 16; ++t) {
            float d2 = redd[t * MT + tid];
            int   k2 = redk[t * MT + tid];
            if (d2 < bd || (d2 == bd && k2 < bk)) { bd = d2; bk = k2; }
        }
        wsd[(size_t)split * NTOK + tok0 + tid] = bd;
        wsk[(size_t)split * NTOK + tok0 + tid] = bk;
    }
}

// ---------------- kernel 4: merge splits, emit indices, accumulate loss sum ----------------
__global__ __launch_bounds__(256) void k4_merge(const float* __restrict__ wsd,
                                                const int* __restrict__ wsk,
                                                float* __restrict__ idxf,
                                                float* __restrict__ S) {
    __shared__ float red[256];
    const int t = blockIdx.x * 256 + threadIdx.x;   // grid = 128 blocks
    float bd = wsd[t];
    int   bk = wsk[t];
#pragma unroll
    for (int s = 1; s < CSPLIT; ++s) {
        float d = wsd[(size_t)s * NTOK + t];
        int   k = wsk[(size_t)s * NTOK + t];
        if (d < bd) { bd = d; bk = k; }   // tie -> lower split = lower index (argmin semantics)
    }
    idxf[t] = (float)bk;
    red[threadIdx.x] = bd;
    __syncthreads();
    for (int o = 128; o > 0; o >>= 1) {
        if (threadIdx.x < o) red[threadIdx.x] += red[threadIdx.x + o];
        __syncthreads();
    }
    if (threadIdx.x == 0) atomicAdd(S, red[0]);
}

// ---------------- kernel 2: scatter z_q = emb[idx] into [b,c,h,w] layout ----------------
__global__ __launch_bounds__(256) void k2_scatter(const float* __restrict__ emb,
                                                  const float* __restrict__ idxf,
                                                  float* __restrict__ zq) {
    __shared__ int ks[64];
    const int tid  = threadIdx.x;
    const int tok0 = blockIdx.x * 64;          // grid = 512 blocks
    const int b    = tok0 >> 10;
    const int hw0  = tok0 & 1023;
    if (tid < 64) ks[tid] = (int)idxf[tok0 + tid];
    __syncthreads();
    const int t4 = (tid & 15) * 4;
    const int ka = ks[t4], kb = ks[t4 + 1], kc = ks[t4 + 2], kd = ks[t4 + 3];
    float* outb = zq + (size_t)b * (CDIM * HW) + hw0 + t4;
    int c = tid >> 4;                          // 16 c per pass, 16 passes
#pragma unroll
    for (int p = 0; p < 16; ++p, c += 16) {
        float4 v;
        v.x = emb[(size_t)ka * CDIM + c];
        v.y = emb[(size_t)kb * CDIM + c];
        v.z = emb[(size_t)kc * CDIM + c];
        v.w = emb[(size_t)kd * CDIM + c];
        *(float4*)(outb + (size_t)c * HW) = v;   // coalesced float4 store
    }
}

// ---------------- kernel 3: the three loss scalars ----------------
// S = sum_n min_k ||z_n - e_k||^2 (quantized d; error ~1e-3 vs ~2% threshold)
__global__ void k3_scalars(const float* __restrict__ S, float* __restrict__ out) {
    const float mse = *S / (float)NELEM;
    out[0] = 1.25f * mse;   // loss
    out[1] = 0.25f * mse;   // commitment_loss
    out[2] = mse;           // codebook_loss
}

extern "C" void kernel_launch(void* const* d_in, const int* in_sizes, int n_in,
                              void* d_out, int out_size, void* d_ws, size_t ws_size,
                              hipStream_t stream) {
    const float* z   = (const float*)d_in[0];   // [32,256,32,32]
    const float* emb = (const float*)d_in[1];   // [4096,256]
    float* out  = (float*)d_out;                // zq(8388608) | 3 scalars | idx(32768) as f32
    float* wsf  = (float*)d_ws;
    float* S      = wsf;                        // 1 float
    float* enorm2 = wsf + 64;                   // 4096
    float* znorm2 = wsf + 64 + CB;              // 32768
    float* wsd    = wsf + 64 + CB + NTOK;       // CSPLIT*32768
    int*   wsk    = (int*)(wsd + (size_t)CSPLIT * NTOK);  // CSPLIT*32768
    float* idxf   = out + NELEM + 3;

    hipLaunchKernelGGL(k0_enorm,  dim3(CB / 256),           dim3(256), 0, stream, emb, enorm2, S);
    hipLaunchKernelGGL(k0z_znorm, dim3(NTOK / 256),         dim3(256), 0, stream, z, znorm2);
    hipLaunchKernelGGL(k1_argmin, dim3(NTOK / MT * CSPLIT), dim3(256), 0, stream,
                       z, emb, enorm2, znorm2, wsd, wsk);
    hipLaunchKernelGGL(k4_merge,  dim3(NTOK / 256),         dim3(256), 0, stream, wsd, wsk, idxf, S);
    hipLaunchKernelGGL(k2_scatter, dim3(NTOK / 64),         dim3(256), 0, stream, emb, idxf, out);
    hipLaunchKernelGGL(k3_scalars, dim3(1), dim3(1), 0, stream, S, out + NELEM);
}

// Round 7
// 407.213 us; speedup vs baseline: 3.3308x; 2.2053x over previous
//
#include <hip/hip_runtime.h>

// Problem constants
#define CDIM 256        // token_size (channels)
#define CB   4096       // codebook size
#define HW   1024       // 32*32
#define NTOK 32768      // tokens
#define NELEM 8388608   // 32*256*32*32
#define MARGIN 3.5e-4f  // screen margin in d-units: ~35 sigma of bf16 dot error,
                        // admits ~0.33 extra candidates/token (see session notes)

typedef float f32x4 __attribute__((ext_vector_type(4)));
typedef short bf16x8 __attribute__((ext_vector_type(8)));
typedef unsigned int u32;

__device__ __forceinline__ unsigned short f2bf(float x) {   // RNE fp32->bf16
    u32 b = __float_as_uint(x);
    return (unsigned short)((b + 0x7fffu + ((b >> 16) & 1u)) >> 16);
}
// order-preserving float <-> uint for atomicMin
__device__ __forceinline__ u32 fenc(float f) {
    u32 b = __float_as_uint(f);
    return (b & 0x80000000u) ? ~b : (b | 0x80000000u);
}
__device__ __forceinline__ float fdec(u32 u) {
    return __uint_as_float((u & 0x80000000u) ? (u & 0x7fffffffu) : ~u);
}

// ---------------- k0z: per-token ||z||^2 + init umin/cnt/S ----------------
__global__ __launch_bounds__(256) void k0z(const float* __restrict__ z,
                                           float* __restrict__ zn,
                                           u32* __restrict__ umin,
                                           u32* __restrict__ cnt,
                                           float* __restrict__ S) {
    const int tok = blockIdx.x * 256 + threadIdx.x;    // grid = 128
    const int b = tok >> 10, hw = tok & 1023;
    const float* zp = z + (size_t)b * (CDIM * HW) + hw;
    float s0 = 0.f, s1 = 0.f, s2 = 0.f, s3 = 0.f;
#pragma unroll 4
    for (int c = 0; c < CDIM; c += 4) {
        float a = zp[(size_t)(c + 0) * HW], b2 = zp[(size_t)(c + 1) * HW];
        float c2 = zp[(size_t)(c + 2) * HW], d2 = zp[(size_t)(c + 3) * HW];
        s0 += a * a; s1 += b2 * b2; s2 += c2 * c2; s3 += d2 * d2;
    }
    zn[tok] = (s0 + s1) + (s2 + s3);
    umin[tok] = 0xFFFFFFFFu;
    cnt[tok] = 0u;
    if (tok == 0) *S = 0.f;
}

// ---------------- k0e: codebook norms + packed bf16 codebook ----------------
// e_hip layout: [cg 0..31][kc 0..7][code 0..127][kk 0..31] bf16
// ROUND-6 BUG: store loop was q<8 (16 shorts) leaving kk 16..31 as 0xAA poison
// -> screen dots missing half the channels -> indices garbage. Must be q<16.
__global__ __launch_bounds__(256) void k0e(const float* __restrict__ emb,
                                           float* __restrict__ enorm2,
                                           unsigned short* __restrict__ e_hip) {
    const int cg = blockIdx.x;                 // grid = 32
    const int tid = threadIdx.x;
    const int code_l = tid >> 1;               // 2 threads per code
    const int code = cg * 128 + code_l;
    float s = 0.f;
#pragma unroll
    for (int kb = 0; kb < 4; ++kb) {
        const int c0 = (tid & 1) * 128 + kb * 32;
        const int kc = c0 >> 5;
        unsigned short tmp[32];
#pragma unroll
        for (int q = 0; q < 8; ++q) {
            float4 v = *(const float4*)(emb + (size_t)code * CDIM + c0 + 4 * q);
            s += v.x * v.x + v.y * v.y + v.z * v.z + v.w * v.w;
            tmp[4 * q + 0] = f2bf(v.x); tmp[4 * q + 1] = f2bf(v.y);
            tmp[4 * q + 2] = f2bf(v.z); tmp[4 * q + 3] = f2bf(v.w);
        }
        unsigned short* dst = e_hip + (((size_t)(cg * 8 + kc) * 128 + code_l) * 32);
#pragma unroll
        for (int q = 0; q < 16; ++q) ((uint*)dst)[q] = *(uint*)&tmp[2 * q];  // all 32 shorts
    }
    s += __shfl_xor(s, 1);
    if ((tid & 1) == 0) enorm2[code] = s;
}

// ---------------- p0: transpose z -> zT fp32 [t][c] + packed bf16 z ----------------
// z_hip layout: [rg 0..255][kc 0..7][tok 0..127][kk 0..31] bf16
__global__ __launch_bounds__(256) void p0(const float* __restrict__ z,
                                          float* __restrict__ zT,
                                          unsigned short* __restrict__ z_hip) {
    __shared__ float T[32][132];
    const int rg = blockIdx.x;                 // grid = 256 (128 tokens each)
    const int tid = threadIdx.x;
    const int b = (rg * 128) >> 10, hw0 = (rg * 128) & 1023;
    const float* zb = z + (size_t)b * (CDIM * HW) + hw0;
    for (int kc = 0; kc < 8; ++kc) {
        const int c0 = kc * 32;
        __syncthreads();
#pragma unroll
        for (int p = 0; p < 16; ++p) {
            const int c = p * 2 + (tid >> 7);
            T[c][tid & 127] = zb[(size_t)(c0 + c) * HW + (tid & 127)];
        }
        __syncthreads();
        const int tt = tid >> 1, h = (tid & 1) * 16;
        float* dstT = zT + (size_t)(rg * 128 + tt) * CDIM + c0 + h;
        unsigned short us[16];
#pragma unroll
        for (int q = 0; q < 4; ++q) {
            float4 v;
            v.x = T[h + 4 * q + 0][tt]; v.y = T[h + 4 * q + 1][tt];
            v.z = T[h + 4 * q + 2][tt]; v.w = T[h + 4 * q + 3][tt];
            ((float4*)dstT)[q] = v;
            us[4 * q + 0] = f2bf(v.x); us[4 * q + 1] = f2bf(v.y);
            us[4 * q + 2] = f2bf(v.z); us[4 * q + 3] = f2bf(v.w);
        }
        unsigned short* d2 = z_hip + (((size_t)(rg * 8 + kc) * 128 + tt) * 32 + h);
#pragma unroll
        for (int q = 0; q < 8; ++q) ((uint*)d2)[q] = *(uint*)&us[2 * q];     // 16 shorts (this thread's half)
    }
}

// Tile: 128 tokens x 128 codes, K=256 in chunks of 32. 4 waves in 2x2; each wave
// 4x4 grid of 16x16x32 MFMAs. A[m=lane&15][k=quad*8+j]; B staged as rows of B^T
// (same pattern, n=lane&15); C: col=lane&15, row=quad*4+reg (m89-verified).

// ---------------- p1: bf16 MFMA screen, per-token global min -> umin ----------------
__global__ __launch_bounds__(256) void p1(const unsigned short* __restrict__ z_hip,
                                          const unsigned short* __restrict__ e_hip,
                                          const float* __restrict__ enorm2,
                                          u32* __restrict__ umin) {
    __shared__ __align__(16) unsigned short As[128 * 32];
    __shared__ __align__(16) unsigned short Bs[128 * 32];
    const int bid = blockIdx.x;                // grid = 8192
    const int rg = bid >> 5, cg = bid & 31;    // consecutive blocks share A-tile (L2)
    const int tid = threadIdx.x;
    const int w = tid >> 6, lane = tid & 63;
    const int quad = lane >> 4, l15 = lane & 15;
    const int rowoff = (w >> 1) * 64, coloff = (w & 1) * 64;

    f32x4 acc[4][4];
#pragma unroll
    for (int i = 0; i < 4; ++i)
#pragma unroll
        for (int j = 0; j < 4; ++j)
#pragma unroll
            for (int e = 0; e < 4; ++e) acc[i][j][e] = 0.f;

    const float4* Ag = (const float4*)(z_hip + (size_t)rg * 8 * 4096);
    const float4* Bg = (const float4*)(e_hip + (size_t)cg * 8 * 4096);
    for (int kc = 0; kc < 8; ++kc) {
        __syncthreads();
        ((float4*)As)[tid] = Ag[kc * 512 + tid];
        ((float4*)As)[tid + 256] = Ag[kc * 512 + tid + 256];
        ((float4*)Bs)[tid] = Bg[kc * 512 + tid];
        ((float4*)Bs)[tid + 256] = Bg[kc * 512 + tid + 256];
        __syncthreads();
        bf16x8 af[4], bfr[4];
#pragma unroll
        for (int ni = 0; ni < 4; ++ni)
            bfr[ni] = *(const bf16x8*)&Bs[(coloff + ni * 16 + l15) * 32 + quad * 8];
#pragma unroll
        for (int mi = 0; mi < 4; ++mi)
            af[mi] = *(const bf16x8*)&As[(rowoff + mi * 16 + l15) * 32 + quad * 8];
#pragma unroll
        for (int mi = 0; mi < 4; ++mi)
#pragma unroll
            for (int ni = 0; ni < 4; ++ni)
                acc[mi][ni] = __builtin_amdgcn_mfma_f32_16x16x32_bf16(
                    af[mi], bfr[ni], acc[mi][ni], 0, 0, 0);
    }
    // epilogue: d~ = en2[col] - 2*dot; per-row (token) min over this block's 128 cols
    float en[4];
#pragma unroll
    for (int ni = 0; ni < 4; ++ni) en[ni] = enorm2[cg * 128 + coloff + ni * 16 + l15];
    float bd[4][4];
#pragma unroll
    for (int mi = 0; mi < 4; ++mi)
#pragma unroll
        for (int r = 0; r < 4; ++r) {
            float best = 1e30f;
#pragma unroll
            for (int ni = 0; ni < 4; ++ni) {
                float d = en[ni] - 2.0f * acc[mi][ni][r];
                best = fminf(best, d);
            }
            bd[mi][r] = best;
        }
#pragma unroll
    for (int s = 1; s < 16; s <<= 1)
#pragma unroll
        for (int mi = 0; mi < 4; ++mi)
#pragma unroll
            for (int r = 0; r < 4; ++r)
                bd[mi][r] = fminf(bd[mi][r], __shfl_xor(bd[mi][r], s));
    if (l15 == 0) {
#pragma unroll
        for (int mi = 0; mi < 4; ++mi)
#pragma unroll
            for (int r = 0; r < 4; ++r) {
                const int t = rg * 128 + rowoff + mi * 16 + quad * 4 + r;
                atomicMin(&umin[t], fenc(bd[mi][r]));
            }
    }
}

// ---------------- p2: same GEMM, collect candidates with d~ <= min + MARGIN ----------------
__global__ __launch_bounds__(256) void p2(const unsigned short* __restrict__ z_hip,
                                          const unsigned short* __restrict__ e_hip,
                                          const float* __restrict__ enorm2,
                                          const u32* __restrict__ umin,
                                          u32* __restrict__ cnt,
                                          int* __restrict__ cand) {
    __shared__ __align__(16) unsigned short As[128 * 32];
    __shared__ __align__(16) unsigned short Bs[128 * 32];
    const int bid = blockIdx.x;
    const int rg = bid >> 5, cg = bid & 31;
    const int tid = threadIdx.x;
    const int w = tid >> 6, lane = tid & 63;
    const int quad = lane >> 4, l15 = lane & 15;
    const int rowoff = (w >> 1) * 64, coloff = (w & 1) * 64;

    f32x4 acc[4][4];
#pragma unroll
    for (int i = 0; i < 4; ++i)
#pragma unroll
        for (int j = 0; j < 4; ++j)
#pragma unroll
            for (int e = 0; e < 4; ++e) acc[i][j][e] = 0.f;

    const float4* Ag = (const float4*)(z_hip + (size_t)rg * 8 * 4096);
    const float4* Bg = (const float4*)(e_hip + (size_t)cg * 8 * 4096);
    for (int kc = 0; kc < 8; ++kc) {
        __syncthreads();
        ((float4*)As)[tid] = Ag[kc * 512 + tid];
        ((float4*)As)[tid + 256] = Ag[kc * 512 + tid + 256];
        ((float4*)Bs)[tid] = Bg[kc * 512 + tid];
        ((float4*)Bs)[tid + 256] = Bg[kc * 512 + tid + 256];
        __syncthreads();
        bf16x8 af[4], bfr[4];
#pragma unroll
        for (int ni = 0; ni < 4; ++ni)
            bfr[ni] = *(const bf16x8*)&Bs[(coloff + ni * 16 + l15) * 32 + quad * 8];
#pragma unroll
        for (int mi = 0; mi < 4; ++mi)
            af[mi] = *(const bf16x8*)&As[(rowoff + mi * 16 + l15) * 32 + quad * 8];
#pragma unroll
        for (int mi = 0; mi < 4; ++mi)
#pragma unroll
            for (int ni = 0; ni < 4; ++ni)
                acc[mi][ni] = __builtin_amdgcn_mfma_f32_16x16x32_bf16(
                    af[mi], bfr[ni], acc[mi][ni], 0, 0, 0);
    }
    __syncthreads();
    if (tid < 128) ((u32*)As)[tid] = umin[rg * 128 + tid];
    __syncthreads();
    float en[4];
#pragma unroll
    for (int ni = 0; ni < 4; ++ni) en[ni] = enorm2[cg * 128 + coloff + ni * 16 + l15];
#pragma unroll
    for (int mi = 0; mi < 4; ++mi)
#pragma unroll
        for (int r = 0; r < 4; ++r) {
            const int trow = rowoff + mi * 16 + quad * 4 + r;
            const float thr = fdec(((u32*)As)[trow]) + MARGIN;
            const int t = rg * 128 + trow;
#pragma unroll
            for (int ni = 0; ni < 4; ++ni) {
                float d = en[ni] - 2.0f * acc[mi][ni][r];
                if (d <= thr) {
                    const int k = cg * 128 + coloff + ni * 16 + l15;
                    u32 pos = atomicAdd(&cnt[t], 1u);
                    if (pos < 8u) cand[t * 8 + pos] = k;
                }
            }
        }
}

// ---------------- k5: exact fp32 rescore of candidates (reference rounding chain) ----------------
__global__ __launch_bounds__(256) void k5(const float* __restrict__ zT,
                                          const float* __restrict__ emb,
                                          const float* __restrict__ enorm2,
                                          const float* __restrict__ zn,
                                          const u32* __restrict__ cnt,
                                          const int* __restrict__ cand,
                                          float* __restrict__ idxf) {
    const int t = (blockIdx.x * 256 + threadIdx.x) >> 6;   // wave per token, grid = 8192
    const int lane = threadIdx.x & 63;
    u32 n = cnt[t]; if (n > 8u) n = 8u;
    const float4 za = ((const float4*)(zT + (size_t)t * CDIM))[lane];
    const float znv = zn[t];
    float bdv = 1e30f; int bk = 0x7fffffff;
    for (u32 i = 0; i < n; ++i) {
        const int k = cand[t * 8 + i];
        const float4 ea = ((const float4*)(emb + (size_t)k * CDIM))[lane];
        float p = za.x * ea.x + za.y * ea.y + za.z * ea.z + za.w * ea.w;
#pragma unroll
        for (int s = 1; s < 64; s <<= 1) p += __shfl_xor(p, s);
        const float t1 = znv + enorm2[k];         // fl(zn + en)  — reference chain
        const float d = t1 - 2.0f * p;            // fl(t1 - 2 dot)
        if (d < bdv || (d == bdv && k < bk)) { bdv = d; bk = k; }
    }
    if (lane == 0) idxf[t] = (float)bk;
}

// ---------------- k2: scatter z_q = emb[idx] + exact fused loss sum ----------------
__global__ __launch_bounds__(256) void k2(const float* __restrict__ emb,
                                          const float* __restrict__ idxf,
                                          const float* __restrict__ z,
                                          float* __restrict__ zq,
                                          float* __restrict__ S) {
    __shared__ int ks[64];
    __shared__ float red[256];
    const int tid = threadIdx.x;
    const int tok0 = blockIdx.x * 64;          // grid = 512
    const int b = tok0 >> 10, hw0 = tok0 & 1023;
    if (tid < 64) ks[tid] = (int)idxf[tok0 + tid];
    __syncthreads();
    const int t4 = (tid & 15) * 4;
    const int ka = ks[t4], kb = ks[t4 + 1], kc = ks[t4 + 2], kd = ks[t4 + 3];
    const size_t base = (size_t)b * (CDIM * HW) + hw0 + t4;
    float accu = 0.f;
    int c = tid >> 4;
#pragma unroll
    for (int p = 0; p < 16; ++p, c += 16) {
        float4 v;
        v.x = emb[(size_t)ka * CDIM + c];
        v.y = emb[(size_t)kb * CDIM + c];
        v.z = emb[(size_t)kc * CDIM + c];
        v.w = emb[(size_t)kd * CDIM + c];
        float4 zv = *(const float4*)(z + base + (size_t)c * HW);
        float dx = v.x - zv.x, dy = v.y - zv.y, dz = v.z - zv.z, dw = v.w - zv.w;
        accu += dx * dx + dy * dy + dz * dz + dw * dw;
        *(float4*)(zq + base + (size_t)c * HW) = v;
    }
    red[tid] = accu;
    __syncthreads();
    for (int o = 128; o > 0; o >>= 1) {
        if (tid < o) red[tid] += red[tid + o];
        __syncthreads();
    }
    if (tid == 0) atomicAdd(S, red[0]);
}

// ---------------- k3: the three loss scalars ----------------
__global__ void k3(const float* __restrict__ S, float* __restrict__ out) {
    const float mse = *S / (float)NELEM;
    out[0] = 1.25f * mse;   // loss
    out[1] = 0.25f * mse;   // commitment_loss
    out[2] = mse;           // codebook_loss
}

extern "C" void kernel_launch(void* const* d_in, const int* in_sizes, int n_in,
                              void* d_out, int out_size, void* d_ws, size_t ws_size,
                              hipStream_t stream) {
    const float* z   = (const float*)d_in[0];   // [32,256,32,32]
    const float* emb = (const float*)d_in[1];   // [4096,256]
    float* out = (float*)d_out;                 // zq | 3 scalars | idx (as f32)
    char* w = (char*)d_ws;

    float* S      = (float*)w;                       w += 256;
    float* zn     = (float*)w;                       w += NTOK * 4;
    float* enorm2 = (float*)w;                       w += CB * 4;
    u32*   umin   = (u32*)w;                         w += NTOK * 4;
    u32*   cnt    = (u32*)w;                         w += NTOK * 4;
    int*   cand   = (int*)w;                         w += NTOK * 8 * 4;
    float* zT     = (float*)w;                       w += (size_t)NTOK * CDIM * 4;
    unsigned short* z_hip = (unsigned short*)w;      w += (size_t)NTOK * CDIM * 2;
    unsigned short* e_hip = (unsigned short*)w;      w += (size_t)CB * CDIM * 2;
    float* idxf = out + NELEM + 3;

    hipLaunchKernelGGL(k0z, dim3(NTOK / 256), dim3(256), 0, stream, z, zn, umin, cnt, S);
    hipLaunchKernelGGL(k0e, dim3(CB / 128),   dim3(256), 0, stream, emb, enorm2, e_hip);
    hipLaunchKernelGGL(p0,  dim3(NTOK / 128), dim3(256), 0, stream, z, zT, z_hip);
    hipLaunchKernelGGL(p1,  dim3((NTOK / 128) * (CB / 128)), dim3(256), 0, stream,
                       z_hip, e_hip, enorm2, umin);
    hipLaunchKernelGGL(p2,  dim3((NTOK / 128) * (CB / 128)), dim3(256), 0, stream,
                       z_hip, e_hip, enorm2, umin, cnt, cand);
    hipLaunchKernelGGL(k5,  dim3(NTOK / 4),   dim3(256), 0, stream,
                       zT, emb, enorm2, zn, cnt, cand, idxf);
    hipLaunchKernelGGL(k2,  dim3(NTOK / 64),  dim3(256), 0, stream, emb, idxf, z, out, S);
    hipLaunchKernelGGL(k3,  dim3(1), dim3(1), 0, stream, S, out + NELEM);
}

// Round 8
// 363.654 us; speedup vs baseline: 3.7298x; 1.1198x over previous
//
#include <hip/hip_runtime.h>

// Problem constants
#define CDIM 256        // token_size (channels)
#define CB   4096       // codebook size
#define HW   1024       // 32*32
#define NTOK 32768      // tokens
#define NELEM 8388608   // 32*256*32*32
#define MARGIN 3.5e-4f  // screen margin in d-units (see session notes)

typedef float f32x4 __attribute__((ext_vector_type(4)));
typedef short bf16x8 __attribute__((ext_vector_type(8)));
typedef unsigned int u32;

__device__ __forceinline__ unsigned short f2bf(float x) {   // RNE fp32->bf16
    u32 b = __float_as_uint(x);
    return (unsigned short)((b + 0x7fffu + ((b >> 16) & 1u)) >> 16);
}
// order-preserving float <-> uint for atomicMin
__device__ __forceinline__ u32 fenc(float f) {
    u32 b = __float_as_uint(f);
    return (b & 0x80000000u) ? ~b : (b | 0x80000000u);
}
__device__ __forceinline__ float fdec(u32 u) {
    return __uint_as_float((u & 0x80000000u) ? (u & 0x7fffffffu) : ~u);
}
// async global->LDS, 16B per lane; lds dest = wave-uniform base + lane*16
__device__ __forceinline__ void gl_lds16(const void* g, void* l) {
    __builtin_amdgcn_global_load_lds(
        (const __attribute__((address_space(1))) u32*)g,
        (__attribute__((address_space(3))) u32*)l, 16, 0, 0);
}

// Packed-tile layouts (z_hip: [rg][kc][row 0..127][32 bf16], e_hip same with cg/code).
// Within a row, the four 16B quad-chunks are stored XOR-swizzled: quad q data at
// position q^(row&3). Makes MFMA fragment ds_read_b128 bank-minimal per half-wave.

// ---------------- k0e: codebook norms + packed/swizzled bf16 codebook + S=0 ----------------
__global__ __launch_bounds__(256) void k0e(const float* __restrict__ emb,
                                           float* __restrict__ enorm2,
                                           unsigned short* __restrict__ e_hip,
                                           float* __restrict__ S) {
    const int cg = blockIdx.x;                 // grid = 32
    const int tid = threadIdx.x;
    const int code_l = tid >> 1;               // 2 threads per code
    const int code = cg * 128 + code_l;
    float s = 0.f;
#pragma unroll
    for (int kb = 0; kb < 4; ++kb) {
        const int c0 = (tid & 1) * 128 + kb * 32;
        const int kc = c0 >> 5;
        __align__(16) unsigned short tmp[32];
#pragma unroll
        for (int q = 0; q < 8; ++q) {
            float4 v = *(const float4*)(emb + (size_t)code * CDIM + c0 + 4 * q);
            s += v.x * v.x + v.y * v.y + v.z * v.z + v.w * v.w;
            tmp[4 * q + 0] = f2bf(v.x); tmp[4 * q + 1] = f2bf(v.y);
            tmp[4 * q + 2] = f2bf(v.z); tmp[4 * q + 3] = f2bf(v.w);
        }
        uint4* dst4 = (uint4*)(e_hip + (((size_t)(cg * 8 + kc) * 128 + code_l) * 32));
#pragma unroll
        for (int q = 0; q < 4; ++q)
            dst4[q ^ (code_l & 3)] = *(uint4*)&tmp[8 * q];   // XOR-swizzled quad chunks
    }
    s += __shfl_xor(s, 1);
    if ((tid & 1) == 0) enorm2[code] = s;
    if (cg == 0 && tid == 0) *S = 0.f;
}

// ---------------- p0: transpose z -> zT fp32 + packed/swizzled bf16 z + zn/umin/cnt ----------------
__global__ __launch_bounds__(256) void p0(const float* __restrict__ z,
                                          float* __restrict__ zT,
                                          unsigned short* __restrict__ z_hip,
                                          float* __restrict__ zn,
                                          u32* __restrict__ umin,
                                          u32* __restrict__ cnt) {
    __shared__ float T[32][132];
    const int rg = blockIdx.x;                 // grid = 256 (128 tokens each)
    const int tid = threadIdx.x;
    const int b = (rg * 128) >> 10, hw0 = (rg * 128) & 1023;
    const float* zb = z + (size_t)b * (CDIM * HW) + hw0;
    const int tt = tid >> 1, h = (tid & 1) * 16;   // token, channel-half within chunk
    const int q0 = h >> 3;                         // first quad handled (0 or 2)
    float zsq = 0.f;
    for (int kc = 0; kc < 8; ++kc) {
        const int c0 = kc * 32;
        __syncthreads();
#pragma unroll
        for (int p = 0; p < 16; ++p) {
            const int c = p * 2 + (tid >> 7);
            T[c][tid & 127] = zb[(size_t)(c0 + c) * HW + (tid & 127)];
        }
        __syncthreads();
        float* dstT = zT + (size_t)(rg * 128 + tt) * CDIM + c0 + h;
        __align__(16) unsigned short us[16];
#pragma unroll
        for (int q = 0; q < 4; ++q) {
            float4 v;
            v.x = T[h + 4 * q + 0][tt]; v.y = T[h + 4 * q + 1][tt];
            v.z = T[h + 4 * q + 2][tt]; v.w = T[h + 4 * q + 3][tt];
            ((float4*)dstT)[q] = v;
            zsq += v.x * v.x + v.y * v.y + v.z * v.z + v.w * v.w;
            us[4 * q + 0] = f2bf(v.x); us[4 * q + 1] = f2bf(v.y);
            us[4 * q + 2] = f2bf(v.z); us[4 * q + 3] = f2bf(v.w);
        }
        uint4* d4 = (uint4*)(z_hip + (((size_t)(rg * 8 + kc) * 128 + tt) * 32));
        d4[q0 ^ (tt & 3)]       = *(uint4*)&us[0];   // XOR-swizzled quad chunks
        d4[(q0 + 1) ^ (tt & 3)] = *(uint4*)&us[8];
    }
    zsq += __shfl_xor(zsq, 1);     // fp32 sum order arbitrary: argmin translation-invariant
    if ((tid & 1) == 0) {
        const int t = rg * 128 + tt;
        zn[t] = zsq; umin[t] = 0xFFFFFFFFu; cnt[t] = 0u;
    }
}

// Tile: 128 tokens x 128 codes, K=256 in 8 chunks of 32. 4 waves in 2x2; each wave
// 4x4 grid of 16x16x32 MFMAs. A[m=lane&15][k=quad*8+j]; B as B^T rows (n=lane&15);
// C: col=lane&15, row=quad*4+reg (m89-verified). Staging via global_load_lds w=16.

// ---------------- p1: bf16 MFMA screen, per-token global min -> umin ----------------
__global__ __launch_bounds__(256) void p1(const unsigned short* __restrict__ z_hip,
                                          const unsigned short* __restrict__ e_hip,
                                          const float* __restrict__ enorm2,
                                          u32* __restrict__ umin) {
    __shared__ __align__(16) unsigned short As[128 * 32];
    __shared__ __align__(16) unsigned short Bs[128 * 32];
    const int bid = blockIdx.x;                // grid = 8192
    const int rg = bid >> 5, cg = bid & 31;    // consecutive blocks share A-tile (L2)
    const int tid = threadIdx.x;
    const int w = tid >> 6, lane = tid & 63;
    const int quad = lane >> 4, l15 = lane & 15;
    const int rowoff = (w >> 1) * 64, coloff = (w & 1) * 64;
    const int swz = (quad ^ (l15 & 3)) * 8;    // de-swizzle for fragment reads

    f32x4 acc[4][4];
#pragma unroll
    for (int i = 0; i < 4; ++i)
#pragma unroll
        for (int j = 0; j < 4; ++j)
#pragma unroll
            for (int e = 0; e < 4; ++e) acc[i][j][e] = 0.f;

    const char* gA = (const char*)z_hip + ((size_t)rg << 16) + w * 2048 + lane * 16;
    const char* gB = (const char*)e_hip + ((size_t)cg << 16) + w * 2048 + lane * 16;
    char* lA = (char*)As + w * 2048;           // wave-uniform LDS base
    char* lB = (char*)Bs + w * 2048;
    for (int kc = 0; kc < 8; ++kc) {
        __syncthreads();
        gl_lds16(gA, lA);           gl_lds16(gA + 1024, lA + 1024);
        gl_lds16(gB, lB);           gl_lds16(gB + 1024, lB + 1024);
        gA += 8192; gB += 8192;
        __syncthreads();
        bf16x8 af[4], bfr[4];
#pragma unroll
        for (int ni = 0; ni < 4; ++ni)
            bfr[ni] = *(const bf16x8*)&Bs[(coloff + ni * 16 + l15) * 32 + swz];
#pragma unroll
        for (int mi = 0; mi < 4; ++mi)
            af[mi] = *(const bf16x8*)&As[(rowoff + mi * 16 + l15) * 32 + swz];
#pragma unroll
        for (int mi = 0; mi < 4; ++mi)
#pragma unroll
            for (int ni = 0; ni < 4; ++ni)
                acc[mi][ni] = __builtin_amdgcn_mfma_f32_16x16x32_bf16(
                    af[mi], bfr[ni], acc[mi][ni], 0, 0, 0);
    }
    // epilogue: d~ = en2[col] - 2*dot; per-token min over this block's 128 cols
    float en[4];
#pragma unroll
    for (int ni = 0; ni < 4; ++ni) en[ni] = enorm2[cg * 128 + coloff + ni * 16 + l15];
    float bd[4][4];
#pragma unroll
    for (int mi = 0; mi < 4; ++mi)
#pragma unroll
        for (int r = 0; r < 4; ++r) {
            float best = 1e30f;
#pragma unroll
            for (int ni = 0; ni < 4; ++ni)
                best = fminf(best, en[ni] - 2.0f * acc[mi][ni][r]);
            bd[mi][r] = best;
        }
#pragma unroll
    for (int s = 1; s < 16; s <<= 1)
#pragma unroll
        for (int mi = 0; mi < 4; ++mi)
#pragma unroll
            for (int r = 0; r < 4; ++r)
                bd[mi][r] = fminf(bd[mi][r], __shfl_xor(bd[mi][r], s));
    if (l15 == 0) {
#pragma unroll
        for (int mi = 0; mi < 4; ++mi)
#pragma unroll
            for (int r = 0; r < 4; ++r) {
                const int t = rg * 128 + rowoff + mi * 16 + quad * 4 + r;
                atomicMin(&umin[t], fenc(bd[mi][r]));
            }
    }
}

// ---------------- p2: same GEMM, collect candidates with d~ <= min + MARGIN ----------------
__global__ __launch_bounds__(256) void p2(const unsigned short* __restrict__ z_hip,
                                          const unsigned short* __restrict__ e_hip,
                                          const float* __restrict__ enorm2,
                                          const u32* __restrict__ umin,
                                          u32* __restrict__ cnt,
                                          int* __restrict__ cand) {
    __shared__ __align__(16) unsigned short As[128 * 32];
    __shared__ __align__(16) unsigned short Bs[128 * 32];
    const int bid = blockIdx.x;
    const int rg = bid >> 5, cg = bid & 31;
    const int tid = threadIdx.x;
    const int w = tid >> 6, lane = tid & 63;
    const int quad = lane >> 4, l15 = lane & 15;
    const int rowoff = (w >> 1) * 64, coloff = (w & 1) * 64;
    const int swz = (quad ^ (l15 & 3)) * 8;

    f32x4 acc[4][4];
#pragma unroll
    for (int i = 0; i < 4; ++i)
#pragma unroll
        for (int j = 0; j < 4; ++j)
#pragma unroll
            for (int e = 0; e < 4; ++e) acc[i][j][e] = 0.f;

    const char* gA = (const char*)z_hip + ((size_t)rg << 16) + w * 2048 + lane * 16;
    const char* gB = (const char*)e_hip + ((size_t)cg << 16) + w * 2048 + lane * 16;
    char* lA = (char*)As + w * 2048;
    char* lB = (char*)Bs + w * 2048;
    for (int kc = 0; kc < 8; ++kc) {
        __syncthreads();
        gl_lds16(gA, lA);           gl_lds16(gA + 1024, lA + 1024);
        gl_lds16(gB, lB);           gl_lds16(gB + 1024, lB + 1024);
        gA += 8192; gB += 8192;
        __syncthreads();
        bf16x8 af[4], bfr[4];
#pragma unroll
        for (int ni = 0; ni < 4; ++ni)
            bfr[ni] = *(const bf16x8*)&Bs[(coloff + ni * 16 + l15) * 32 + swz];
#pragma unroll
        for (int mi = 0; mi < 4; ++mi)
            af[mi] = *(const bf16x8*)&As[(rowoff + mi * 16 + l15) * 32 + swz];
#pragma unroll
        for (int mi = 0; mi < 4; ++mi)
#pragma unroll
            for (int ni = 0; ni < 4; ++ni)
                acc[mi][ni] = __builtin_amdgcn_mfma_f32_16x16x32_bf16(
                    af[mi], bfr[ni], acc[mi][ni], 0, 0, 0);
    }
    __syncthreads();
    if (tid < 128) ((u32*)As)[tid] = umin[rg * 128 + tid];
    __syncthreads();
    float en[4];
#pragma unroll
    for (int ni = 0; ni < 4; ++ni) en[ni] = enorm2[cg * 128 + coloff + ni * 16 + l15];
#pragma unroll
    for (int mi = 0; mi < 4; ++mi)
#pragma unroll
        for (int r = 0; r < 4; ++r) {
            const int trow = rowoff + mi * 16 + quad * 4 + r;
            const float thr = fdec(((u32*)As)[trow]) + MARGIN;
            const int t = rg * 128 + trow;
#pragma unroll
            for (int ni = 0; ni < 4; ++ni) {
                float d = en[ni] - 2.0f * acc[mi][ni][r];
                if (d <= thr) {
                    const int k = cg * 128 + coloff + ni * 16 + l15;
                    u32 pos = atomicAdd(&cnt[t], 1u);
                    if (pos < 8u) cand[t * 8 + pos] = k;
                }
            }
        }
}

// ---------------- k5: exact fp32 rescore of candidates (reference rounding chain) ----------------
__global__ __launch_bounds__(256) void k5(const float* __restrict__ zT,
                                          const float* __restrict__ emb,
                                          const float* __restrict__ enorm2,
                                          const float* __restrict__ zn,
                                          const u32* __restrict__ cnt,
                                          const int* __restrict__ cand,
                                          float* __restrict__ idxf) {
    const int t = (blockIdx.x * 256 + threadIdx.x) >> 6;   // wave per token, grid = 8192
    const int lane = threadIdx.x & 63;
    u32 n = cnt[t]; if (n > 8u) n = 8u;
    const float4 za = ((const float4*)(zT + (size_t)t * CDIM))[lane];
    const float znv = zn[t];
    float bdv = 1e30f; int bk = 0x7fffffff;
    for (u32 i = 0; i < n; ++i) {
        const int k = cand[t * 8 + i];
        const float4 ea = ((const float4*)(emb + (size_t)k * CDIM))[lane];
        float p = za.x * ea.x + za.y * ea.y + za.z * ea.z + za.w * ea.w;
#pragma unroll
        for (int s = 1; s < 64; s <<= 1) p += __shfl_xor(p, s);
        const float t1 = znv + enorm2[k];         // fl(zn + en)  — reference chain
        const float d = t1 - 2.0f * p;            // fl(t1 - 2 dot)
        if (d < bdv || (d == bdv && k < bk)) { bdv = d; bk = k; }
    }
    if (lane == 0) idxf[t] = (float)bk;
}

// ---------------- k2: scatter z_q = emb[idx] + exact fused loss sum ----------------
__global__ __launch_bounds__(256) void k2(const float* __restrict__ emb,
                                          const float* __restrict__ idxf,
                                          const float* __restrict__ z,
                                          float* __restrict__ zq,
                                          float* __restrict__ S) {
    __shared__ int ks[64];
    __shared__ float red[256];
    const int tid = threadIdx.x;
    const int tok0 = blockIdx.x * 64;          // grid = 512
    const int b = tok0 >> 10, hw0 = tok0 & 1023;
    if (tid < 64) ks[tid] = (int)idxf[tok0 + tid];
    __syncthreads();
    const int t4 = (tid & 15) * 4;
    const int ka = ks[t4], kb = ks[t4 + 1], kc = ks[t4 + 2], kd = ks[t4 + 3];
    const size_t base = (size_t)b * (CDIM * HW) + hw0 + t4;
    float accu = 0.f;
    int c = tid >> 4;
#pragma unroll
    for (int p = 0; p < 16; ++p, c += 16) {
        float4 v;
        v.x = emb[(size_t)ka * CDIM + c];
        v.y = emb[(size_t)kb * CDIM + c];
        v.z = emb[(size_t)kc * CDIM + c];
        v.w = emb[(size_t)kd * CDIM + c];
        float4 zv = *(const float4*)(z + base + (size_t)c * HW);
        float dx = v.x - zv.x, dy = v.y - zv.y, dz = v.z - zv.z, dw = v.w - zv.w;
        accu += dx * dx + dy * dy + dz * dz + dw * dw;
        *(float4*)(zq + base + (size_t)c * HW) = v;
    }
    red[tid] = accu;
    __syncthreads();
    for (int o = 128; o > 0; o >>= 1) {
        if (tid < o) red[tid] += red[tid + o];
        __syncthreads();
    }
    if (tid == 0) atomicAdd(S, red[0]);
}

// ---------------- k3: the three loss scalars ----------------
__global__ void k3(const float* __restrict__ S, float* __restrict__ out) {
    const float mse = *S / (float)NELEM;
    out[0] = 1.25f * mse;   // loss
    out[1] = 0.25f * mse;   // commitment_loss
    out[2] = mse;           // codebook_loss
}

extern "C" void kernel_launch(void* const* d_in, const int* in_sizes, int n_in,
                              void* d_out, int out_size, void* d_ws, size_t ws_size,
                              hipStream_t stream) {
    const float* z   = (const float*)d_in[0];   // [32,256,32,32]
    const float* emb = (const float*)d_in[1];   // [4096,256]
    float* out = (float*)d_out;                 // zq | 3 scalars | idx (as f32)
    char* w = (char*)d_ws;

    float* S      = (float*)w;                       w += 256;
    float* zn     = (float*)w;                       w += NTOK * 4;
    float* enorm2 = (float*)w;                       w += CB * 4;
    u32*   umin   = (u32*)w;                         w += NTOK * 4;
    u32*   cnt    = (u32*)w;                         w += NTOK * 4;
    int*   cand   = (int*)w;                         w += NTOK * 8 * 4;
    float* zT     = (float*)w;                       w += (size_t)NTOK * CDIM * 4;
    unsigned short* z_hip = (unsigned short*)w;      w += (size_t)NTOK * CDIM * 2;
    unsigned short* e_hip = (unsigned short*)w;      w += (size_t)CB * CDIM * 2;
    float* idxf = out + NELEM + 3;

    hipLaunchKernelGGL(k0e, dim3(CB / 128),   dim3(256), 0, stream, emb, enorm2, e_hip, S);
    hipLaunchKernelGGL(p0,  dim3(NTOK / 128), dim3(256), 0, stream, z, zT, z_hip, zn, umin, cnt);
    hipLaunchKernelGGL(p1,  dim3((NTOK / 128) * (CB / 128)), dim3(256), 0, stream,
                       z_hip, e_hip, enorm2, umin);
    hipLaunchKernelGGL(p2,  dim3((NTOK / 128) * (CB / 128)), dim3(256), 0, stream,
                       z_hip, e_hip, enorm2, umin, cnt, cand);
    hipLaunchKernelGGL(k5,  dim3(NTOK / 4),   dim3(256), 0, stream,
                       zT, emb, enorm2, zn, cnt, cand, idxf);
    hipLaunchKernelGGL(k2,  dim3(NTOK / 64),  dim3(256), 0, stream, emb, idxf, z, out, S);
    hipLaunchKernelGGL(k3,  dim3(1), dim3(1), 0, stream, S, out + NELEM);
}